// Round 9
// baseline (553.694 us; speedup 1.0000x reference)
//
#include <hip/hip_runtime.h>

#define NN 10000
#define NE 160000
#define INV_SQRT3f 0.57735026918962576f
#define INV_SQRT2f 0.70710678118654752f

typedef short bshort8 __attribute__((ext_vector_type(8)));
typedef float floatx4 __attribute__((ext_vector_type(4)));
#define MFMA16(a,b,c) __builtin_amdgcn_mfma_f32_16x16x32_bf16((a),(b),(c),0,0,0)

__device__ __forceinline__ float sigm(float x){ return 1.f/(1.f+__expf(-x)); }
__device__ __forceinline__ float siluf(float x){ return x*sigm(x); }
__device__ __forceinline__ float sleaky(float x){ return 0.6f*x + 0.4f*x*(2.f*sigm(x)-1.f); }
__device__ __forceinline__ unsigned short f2bf(float f){
  unsigned u = __float_as_uint(f);
  u += 0x7FFF + ((u>>16)&1);
  return (unsigned short)(u>>16);
}
__device__ __forceinline__ float bf2f(unsigned short h){
  return __uint_as_float(((unsigned)h)<<16);
}

// swizzled-weight segment offsets (in ushorts)
#define O_W1   0
#define O_W2   2048
#define O_WAS  30720
#define O_WAVT 67584
#define O_WAVB 75776
#define O_WVS  83968
#define O_WVVT 108544
#define O_WVVB 116736
#define O_WALP 124928
#define O_WSS  149504
#define O_WDS  165888
#define O_WSV  182272
#define O_WDV  186368
#define O_WPS  190464
#define O_WPV  206848
#define SWZ_TOTAL 210944

// ---------------------------------------------------------------- init
__global__ __launch_bounds__(256) void k_init(float* __restrict__ num,
                                              float* __restrict__ den,
                                              int* __restrict__ cnt) {
  int i = blockIdx.x*256 + threadIdx.x;
  if (i < NN*320) num[i] = 0.f;
  if (i < NN*8) den[i] = 0.f;
  if (i < NN) cnt[i] = 0;
}

// ---------------------------------------------------------------- counting sort of edges by dst
__global__ __launch_bounds__(256) void k_hist(const int* __restrict__ edst,
                                              int* __restrict__ cnt) {
  int e = blockIdx.x*256 + threadIdx.x;
  if (e < NE) atomicAdd(&cnt[edst[e]], 1);
}

__global__ __launch_bounds__(256) void k_scan(const int* __restrict__ cnt,
                                              int* __restrict__ offs) {
  __shared__ int wsum[4];
  const int tid = threadIdx.x;
  const int lane = tid & 63, wave = tid >> 6;
  int v[40]; int s = 0;
  #pragma unroll
  for (int j=0;j<40;j++){ int i = tid*40+j; v[j] = (i<NN)?cnt[i]:0; s += v[j]; }
  int incl = s;
  #pragma unroll
  for (int d=1; d<64; d<<=1) { int t = __shfl_up(incl, d, 64); if (lane>=d) incl += t; }
  if (lane==63) wsum[wave] = incl;
  __syncthreads();
  int wbase = 0;
  for (int w=0; w<wave; ++w) wbase += wsum[w];
  int excl = wbase + incl - s;
  #pragma unroll
  for (int j=0;j<40;j++){ int i = tid*40+j; if (i<NN) offs[i] = excl; excl += v[j]; }
}

__global__ __launch_bounds__(256) void k_scatter(const int* __restrict__ edst,
                                                 int* __restrict__ offs,
                                                 int* __restrict__ perm) {
  int e = blockIdx.x*256 + threadIdx.x;
  if (e < NE) {
    int pos = atomicAdd(&offs[edst[e]], 1);
    perm[pos] = e;
  }
}

// ---------------------------------------------------------------- weight pre-swizzle to MFMA B-frag layout (bf16)
__global__ __launch_bounds__(256) void k_prep(
    const float* __restrict__ W1, const float* __restrict__ W2,
    const float* __restrict__ WAs, const float* __restrict__ WAv,
    const float* __restrict__ WVs, const float* __restrict__ WVv,
    const float* __restrict__ WAl,
    const float* __restrict__ WSs, const float* __restrict__ WDs,
    const float* __restrict__ WSv, const float* __restrict__ WDv,
    const float* __restrict__ WPs, const float* __restrict__ WPv,
    unsigned short* __restrict__ swz) {
  int s = blockIdx.x*256 + threadIdx.x;
  if (s >= SWZ_TOTAL) return;
  const float* src; int base, N, KT, rowOff;
  if      (s < 2048)  { base=O_W1;   src=W1;  N=64;  KT=1; rowOff=0; }
  else if (s < 30720) { base=O_W2;   src=W2;  N=448; KT=2; rowOff=0; }
  else if (s < 67584) { base=O_WAS;  src=WAs; N=192; KT=6; rowOff=0; }
  else if (s < 75776) { base=O_WAVT; src=WAv; N=64;  KT=4; rowOff=0; }
  else if (s < 83968) { base=O_WAVB; src=WAv; N=64;  KT=4; rowOff=128; }
  else if (s < 108544){ base=O_WVS;  src=WVs; N=128; KT=6; rowOff=0; }
  else if (s < 116736){ base=O_WVVT; src=WVv; N=64;  KT=4; rowOff=0; }
  else if (s < 124928){ base=O_WVVB; src=WVv; N=64;  KT=4; rowOff=128; }
  else if (s < 149504){ base=O_WALP; src=WAl; N=128; KT=6; rowOff=0; }
  else if (s < 165888){ base=O_WSS;  src=WSs; N=128; KT=4; rowOff=0; }
  else if (s < 182272){ base=O_WDS;  src=WDs; N=128; KT=4; rowOff=0; }
  else if (s < 186368){ base=O_WSV;  src=WSv; N=64;  KT=2; rowOff=0; }
  else if (s < 190464){ base=O_WDV;  src=WDv; N=64;  KT=2; rowOff=0; }
  else if (s < 206848){ base=O_WPS;  src=WPs; N=128; KT=4; rowOff=0; }
  else                { base=O_WPV;  src=WPv; N=64;  KT=2; rowOff=0; }
  int loc = s - base;
  int j = loc & 7, l = (loc>>3)&63, kt = (loc>>9)%KT, nt = loc/(512*KT);
  int row = kt*32 + (l>>4)*8 + j + rowOff;
  int col = nt*16 + (l&15);
  swz[s] = f2bf(src[row*N + col]);
}

// ---------------------------------------------------------------- node pre via MFMA: 16 nodes/block
__global__ __launch_bounds__(256) void node_pre(
    const float* __restrict__ x, const float* __restrict__ bsrc,
    const unsigned short* __restrict__ swz,
    float* __restrict__ ms_s, float* __restrict__ md_s,
    float* __restrict__ ms_v, float* __restrict__ md_v) {
  __shared__ __align__(16) unsigned short as_[16*136];
  __shared__ __align__(16) unsigned short av[3][16*72];
  const int tid  = threadIdx.x;
  const int lane = tid & 63, wave = tid >> 6;
  const int quad = lane >> 4, l15 = lane & 15;
  const int n0 = blockIdx.x*16;

  #pragma unroll
  for (int it = 0; it < 20; ++it) {
    int idx = tid + it*256;            // 16*320 = 5120
    int n = idx/320, d = idx - n*320;
    float val = x[(n0+n)*320 + d];
    if (d < 128) as_[n*136 + d] = f2bf(val);
    else { int r = d-128; int m = r/3, c = r-3*m; av[c][n*72 + m] = f2bf(val); }
  }
  __syncthreads();

  {  // scalar: 8 n-tiles x 2 mats = 16 jobs, 4/wave
    bshort8 fa[4];
    #pragma unroll
    for (int kt=0;kt<4;kt++) fa[kt] = *(const bshort8*)&as_[l15*136 + kt*32 + quad*8];
    #pragma unroll
    for (int j=0;j<4;j++) {
      int job = wave*4 + j;
      int mat = job>>3, nt = job&7;
      int col = nt*16 + l15;
      float bb = (mat==0) ? bsrc[col] : 0.f;
      floatx4 acc = {bb,bb,bb,bb};
      int base = mat ? O_WDS : O_WSS;
      #pragma unroll
      for (int kt=0;kt<4;kt++)
        acc = MFMA16(fa[kt], *(const bshort8*)&swz[base + ((nt*4+kt)*64+lane)*8], acc);
      float* dst = mat ? md_s : ms_s;
      #pragma unroll
      for (int r=0;r<4;r++) dst[(n0+quad*4+r)*128 + col] = acc[r];
    }
  }
  {  // vector: 4 n-tiles x 2 mats x 3 c = 24 jobs, 6/wave
    bshort8 fv[3][2];
    #pragma unroll
    for (int c=0;c<3;c++)
      #pragma unroll
      for (int kt=0;kt<2;kt++)
        fv[c][kt] = *(const bshort8*)&av[c][l15*72 + kt*32 + quad*8];
    #pragma unroll
    for (int j=0;j<6;j++) {
      int job = wave*6 + j;
      int mat = job/12, rem = job - mat*12;
      int c = rem>>2, nt = rem&3;
      int col = nt*16 + l15;
      floatx4 acc = {0.f,0.f,0.f,0.f};
      int base = mat ? O_WDV : O_WSV;
      #pragma unroll
      for (int kt=0;kt<2;kt++)
        acc = MFMA16(fv[c][kt], *(const bshort8*)&swz[base + ((nt*2+kt)*64+lane)*8], acc);
      float* dst = mat ? md_v : ms_v;
      #pragma unroll
      for (int r=0;r<4;r++) dst[(n0+quad*4+r)*192 + col*3 + c] = acc[r];
    }
  }
}

// ---------------------------------------------------------------- fused edge pass (unchanged from R8)
__global__ __launch_bounds__(256) void e_all(
    const float* __restrict__ ms_s, const float* __restrict__ md_s,
    const float* __restrict__ ms_v, const float* __restrict__ md_v,
    const int* __restrict__ esrc, const int* __restrict__ edst,
    const int* __restrict__ perm,
    const float* __restrict__ eattr, const float* __restrict__ escal,
    const float* __restrict__ rad_b1, const float* __restrict__ rad_off,
    const float* __restrict__ bact, const float* __restrict__ w_int,
    const float* __restrict__ bval,
    const float* __restrict__ balpha, const float* __restrict__ alpha_dot,
    const unsigned short* __restrict__ swz,
    float* __restrict__ den, float* __restrict__ num) {
  __shared__ __align__(16) char smem[39040];
  unsigned short* sw   = (unsigned short*)smem;           // 16x448
  unsigned short* scb  = (unsigned short*)smem;           // 16x192
  unsigned short* gshb = (unsigned short*)(smem+6144);    // 16x64
  unsigned short* gbb  = (unsigned short*)(smem+8192);    // 3x16x64
  float* vout          = (float*)smem;                    // staging
  unsigned short* ads  = (unsigned short*)(smem+14336);   // 16x200 (ds / vs)
  unsigned short* at1  = (unsigned short*)(smem+20736);   // 16x136 (t1 / t2)
  unsigned short* advb = (unsigned short*)(smem+25088);   // 3x16x136 (dvB / vvB)
  unsigned short* aes  = (unsigned short*)(smem+25088);   // alias (dead pre-B)
  unsigned short* ah   = (unsigned short*)(smem+26368);   // alias (dead pre-B)
  float* s_e0 = (float*)(smem+38144);
  float* s_e1 = (float*)(smem+38208);
  float* s_ex = (float*)(smem+38400);
  int* s_src  = (int*)(smem+38912);
  int* s_dst  = (int*)(smem+38976);
  int* s_eid  = (int*)(smem+38848);
  const int tid  = threadIdx.x;
  const int lane = tid & 63, wave = tid >> 6;
  const int quad = lane >> 4, l15 = lane & 15;
  const int eb = blockIdx.x*16;

  if (tid < 16) {
    int eid = perm[eb+tid];
    s_eid[tid] = eid; s_src[tid] = esrc[eid]; s_dst[tid] = edst[eid];
  }
  __syncthreads();
  if (tid >= 64 && tid < 128) {
    int t = tid-64, e = t>>2, q = t&3;
    float a = eattr[s_eid[e]*4+q];
    if (q == 0) s_e0[e] = a; else s_e1[(q-1)*16+e] = a;
  }
  #pragma unroll
  for (int it = 0; it < 2; ++it) {
    int idx = tid + it*256;
    int e = idx>>5, i = idx&31;
    aes[e*40+i] = f2bf(escal[s_eid[e]*32+i]);
  }
  __syncthreads();

  {
    int nt = wave, col = nt*16 + l15;
    bshort8 a = *(const bshort8*)&aes[l15*40 + quad*8];
    bshort8 b = *(const bshort8*)&swz[O_W1 + (nt*64 + lane)*8];
    float bb = rad_b1[col];
    floatx4 acc = {bb,bb,bb,bb};
    acc = MFMA16(a, b, acc);
    #pragma unroll
    for (int r=0;r<4;r++) ah[(quad*4+r)*72 + col] = f2bf(siluf(acc[r]));
  }
  __syncthreads();

  {
    bshort8 ha0 = *(const bshort8*)&ah[l15*72 + quad*8];
    bshort8 ha1 = *(const bshort8*)&ah[l15*72 + 32 + quad*8];
    #pragma unroll
    for (int t=0;t<7;t++) {
      int nt = wave*7 + t, col = nt*16 + l15;
      float o = rad_off[col];
      floatx4 acc = {o,o,o,o};
      acc = MFMA16(ha0, *(const bshort8*)&swz[O_W2 + ((nt*2+0)*64+lane)*8], acc);
      acc = MFMA16(ha1, *(const bshort8*)&swz[O_W2 + ((nt*2+1)*64+lane)*8], acc);
      #pragma unroll
      for (int r=0;r<4;r++) sw[(quad*4+r)*448 + col] = f2bf(acc[r]);
    }
  }
  __syncthreads();

  #pragma unroll
  for (int it = 0; it < 8; ++it) {
    int t = tid + it*256;
    int m = t&127, e = t>>7;
    float msgs = ms_s[s_src[e]*128+m] + md_s[s_dst[e]*128+m];
    ads[e*200+m] = f2bf(bf2f(sw[e*448+m])*msgs*s_e0[e]);
    at1[e*136+m] = f2bf(bf2f(sw[e*448+128+m])*msgs);
  }
  #pragma unroll
  for (int it = 0; it < 4; ++it) {
    int t = tid + it*256;
    int k = t&63, e = t>>6;
    const float* pa = &ms_v[s_src[e]*192 + k*3];
    const float* pb = &md_v[s_dst[e]*192 + k*3];
    float vx = pa[0]+pb[0], vy = pa[1]+pb[1], vz = pa[2]+pb[2];
    float ex1 = s_e1[0+e], ey1 = s_e1[16+e], ez1 = s_e1[32+e];
    float d = vx*ex1 + vy*ey1 + vz*ez1;
    ads[e*200+128+k] = f2bf(bf2f(sw[e*448+320+k])*d*INV_SQRT3f);
    float w3v = bf2f(sw[e*448+256+k])*s_e0[e];
    float w5  = bf2f(sw[e*448+384+k])*INV_SQRT2f;
    advb[0*2176 + e*136 + k] = f2bf(w3v*vx);
    advb[1*2176 + e*136 + k] = f2bf(w3v*vy);
    advb[2*2176 + e*136 + k] = f2bf(w3v*vz);
    advb[0*2176 + e*136 + 64+k] = f2bf(w5*(vy*ez1 - vz*ey1));
    advb[1*2176 + e*136 + 64+k] = f2bf(w5*(vz*ex1 - vx*ez1));
    advb[2*2176 + e*136 + 64+k] = f2bf(w5*(vx*ey1 - vy*ex1));
  }
  __syncthreads();

  {
    bshort8 fa[6];
    #pragma unroll
    for (int kt=0;kt<6;kt++) fa[kt] = *(const bshort8*)&ads[l15*200 + kt*32 + quad*8];
    #pragma unroll
    for (int t=0;t<2;t++) {
      int h = wave*2 + t;
      int col = h*16 + l15;
      float bb = balpha[col];
      floatx4 acc = {bb,bb,bb,bb};
      #pragma unroll
      for (int kt=0;kt<6;kt++)
        acc = MFMA16(fa[kt], *(const bshort8*)&swz[O_WALP + ((h*6+kt)*64+lane)*8], acc);
      float ad = alpha_dot[col];
      #pragma unroll
      for (int r=0;r<4;r++) {
        float p = sleaky(acc[r])*ad;
        p += __shfl_xor(p, 1);
        p += __shfl_xor(p, 2);
        p += __shfl_xor(p, 4);
        p += __shfl_xor(p, 8);
        if (l15 == 0) {
          int row = quad*4 + r;
          float ex = __expf(p);
          s_ex[row*8+h] = ex;
          atomicAdd(&den[s_dst[row]*8+h], ex);
        }
      }
    }
    #pragma unroll
    for (int t=0;t<3;t++) {
      int nt = wave + 4*t, col = nt*16 + l15;
      float bb = bact[col];
      floatx4 acc = {bb,bb,bb,bb};
      #pragma unroll
      for (int kt=0;kt<6;kt++)
        acc = MFMA16(fa[kt], *(const bshort8*)&swz[O_WAS + ((nt*6+kt)*64+lane)*8], acc);
      #pragma unroll
      for (int r=0;r<4;r++) scb[(quad*4+r)*192 + col] = f2bf(acc[r]);
    }
    bshort8 ft[4];
    #pragma unroll
    for (int kt=0;kt<4;kt++) ft[kt] = *(const bshort8*)&at1[l15*136 + kt*32 + quad*8];
    {
      int nt = wave, col = nt*16 + l15;
      floatx4 acc = {0.f,0.f,0.f,0.f};
      #pragma unroll
      for (int kt=0;kt<4;kt++)
        acc = MFMA16(ft[kt], *(const bshort8*)&swz[O_WAVT + ((nt*4+kt)*64+lane)*8], acc);
      #pragma unroll
      for (int r=0;r<4;r++) gshb[(quad*4+r)*64 + col] = f2bf(acc[r]);
    }
    #pragma unroll
    for (int c=0;c<3;c++) {
      int nt = wave, col = nt*16 + l15;
      floatx4 acc = {0.f,0.f,0.f,0.f};
      #pragma unroll
      for (int kt=0;kt<4;kt++) {
        bshort8 fb = *(const bshort8*)&advb[c*2176 + l15*136 + kt*32 + quad*8];
        acc = MFMA16(fb, *(const bshort8*)&swz[O_WAVB + ((nt*4+kt)*64+lane)*8], acc);
      }
      #pragma unroll
      for (int r=0;r<4;r++) gbb[c*1024 + (quad*4+r)*64 + col] = f2bf(acc[r]);
    }
  }
  __syncthreads();

  #pragma unroll
  for (int it = 0; it < 8; ++it) {
    int t = tid + it*256;
    int m = t&127, e = t>>7;
    float v = siluf(bf2f(scb[e*192+m]));
    ads[e*200+m] = f2bf(w_int[m]*v*s_e0[e]);
    at1[e*136+m] = f2bf(w_int[128+m]*v);
  }
  #pragma unroll
  for (int it = 0; it < 4; ++it) {
    int t = tid + it*256;
    int k = t&63, e = t>>6;
    float sg = sigm(bf2f(scb[e*192+128+k]));
    float gs = bf2f(gshb[e*64+k]);
    float ex1 = s_e1[0+e], ey1 = s_e1[16+e], ez1 = s_e1[32+e];
    float v0 = (gs*ex1 + bf2f(gbb[0*1024 + e*64+k]))*sg;
    float v1 = (gs*ey1 + bf2f(gbb[1*1024 + e*64+k]))*sg;
    float v2 = (gs*ez1 + bf2f(gbb[2*1024 + e*64+k]))*sg;
    float d = v0*ex1 + v1*ey1 + v2*ez1;
    ads[e*200+128+k] = f2bf(w_int[320+k]*d*INV_SQRT3f);
    float w3v = w_int[256+k]*s_e0[e];
    float w5  = w_int[384+k]*INV_SQRT2f;
    advb[0*2176 + e*136 + k] = f2bf(w3v*v0);
    advb[1*2176 + e*136 + k] = f2bf(w3v*v1);
    advb[2*2176 + e*136 + k] = f2bf(w3v*v2);
    advb[0*2176 + e*136 + 64+k] = f2bf(w5*(v1*ez1 - v2*ey1));
    advb[1*2176 + e*136 + 64+k] = f2bf(w5*(v2*ex1 - v0*ez1));
    advb[2*2176 + e*136 + 64+k] = f2bf(w5*(v0*ey1 - v1*ex1));
  }
  __syncthreads();

  {
    bshort8 fa[6];
    #pragma unroll
    for (int kt=0;kt<6;kt++) fa[kt] = *(const bshort8*)&ads[l15*200 + kt*32 + quad*8];
    #pragma unroll
    for (int t=0;t<2;t++) {
      int h = wave + 4*t;
      float bb = bval[h*16 + l15];
      floatx4 acc = {bb,bb,bb,bb};
      #pragma unroll
      for (int kt=0;kt<6;kt++)
        acc = MFMA16(fa[kt], *(const bshort8*)&swz[O_WVS + ((h*6+kt)*64+lane)*8], acc);
      #pragma unroll
      for (int r=0;r<4;r++) {
        int row = quad*4 + r;
        vout[row*128 + h*16 + l15] = acc[r]*s_ex[row*8+h];
      }
    }
  }
  __syncthreads();

  {
    int j = tid & 127, g = tid >> 7;
    int h = j>>4, jj = j&15;
    float acc = 0.f; int cur = s_dst[g*8];
    #pragma unroll
    for (int e = g*8; e < g*8+8; ++e) {
      int d = s_dst[e];
      if (d != cur) { atomicAdd(&num[cur*320 + h*40 + jj], acc); acc = 0.f; cur = d; }
      acc += vout[e*128 + j];
    }
    atomicAdd(&num[cur*320 + h*40 + jj], acc);
  }
  __syncthreads();

  {
    bshort8 ft[4];
    #pragma unroll
    for (int kt=0;kt<4;kt++) ft[kt] = *(const bshort8*)&at1[l15*136 + kt*32 + quad*8];
    floatx4 vsh = {0.f,0.f,0.f,0.f};
    #pragma unroll
    for (int kt=0;kt<4;kt++)
      vsh = MFMA16(ft[kt], *(const bshort8*)&swz[O_WVVT + ((wave*4+kt)*64+lane)*8], vsh);
    int k = wave*16 + l15;
    int h = k>>3, q = k&7;
    #pragma unroll
    for (int c=0;c<3;c++) {
      floatx4 acc = {0.f,0.f,0.f,0.f};
      #pragma unroll
      for (int kt=0;kt<4;kt++) {
        bshort8 fb = *(const bshort8*)&advb[c*2176 + l15*136 + kt*32 + quad*8];
        acc = MFMA16(fb, *(const bshort8*)&swz[O_WVVB + ((wave*4+kt)*64+lane)*8], acc);
      }
      #pragma unroll
      for (int r=0;r<4;r++) {
        int row = quad*4 + r;
        vout[row*192 + h*24 + q*3 + c] =
            (acc[r] + s_e1[c*16+row]*vsh[r]) * s_ex[row*8+h];
      }
    }
  }
  __syncthreads();

  #pragma unroll
  for (int it = 0; it < 2; ++it) {
    int idx = tid + it*256;
    if (idx < 384) {
      int g = idx/192, jj = idx - g*192;
      int h = jj/24, rr = jj - h*24;
      float acc = 0.f; int cur = s_dst[g*8];
      #pragma unroll
      for (int e = g*8; e < g*8+8; ++e) {
        int d = s_dst[e];
        if (d != cur) { atomicAdd(&num[cur*320 + h*40 + 16 + rr], acc); acc = 0.f; cur = d; }
        acc += vout[e*192 + jj];
      }
      atomicAdd(&num[cur*320 + h*40 + 16 + rr], acc);
    }
  }
}

// ---------------------------------------------------------------- node post via MFMA: 16 nodes/block
__global__ __launch_bounds__(256) void node_post(
    const float* __restrict__ num, const float* __restrict__ den,
    const float* __restrict__ bproj, const unsigned short* __restrict__ swz,
    float* __restrict__ out) {
  __shared__ __align__(16) unsigned short ns[16*136];
  __shared__ __align__(16) unsigned short nv[3][16*72];
  const int tid  = threadIdx.x;
  const int lane = tid & 63, wave = tid >> 6;
  const int quad = lane >> 4, l15 = lane & 15;
  const int n0 = blockIdx.x*16;

  #pragma unroll
  for (int it = 0; it < 20; ++it) {
    int idx = tid + it*256;
    int n = idx/320, j = idx - n*320;
    int h = j/40, r = j - h*40;
    float a = num[(n0+n)*320+j] / (den[(n0+n)*8+h] + 1e-16f);
    if (r < 16) ns[n*136 + h*16 + r] = f2bf(a);
    else { int q = r-16; int mm = q/3, c = q-3*mm; nv[c][n*72 + h*8 + mm] = f2bf(a); }
  }
  __syncthreads();

  {  // scalar: Wproj_s, 8 tiles, 2/wave
    bshort8 fa[4];
    #pragma unroll
    for (int kt=0;kt<4;kt++) fa[kt] = *(const bshort8*)&ns[l15*136 + kt*32 + quad*8];
    #pragma unroll
    for (int j=0;j<2;j++) {
      int nt = wave*2 + j;
      int col = nt*16 + l15;
      float bb = bproj[col];
      floatx4 acc = {bb,bb,bb,bb};
      #pragma unroll
      for (int kt=0;kt<4;kt++)
        acc = MFMA16(fa[kt], *(const bshort8*)&swz[O_WPS + ((nt*4+kt)*64+lane)*8], acc);
      #pragma unroll
      for (int r=0;r<4;r++) out[(n0+quad*4+r)*320 + col] = acc[r];
    }
  }
  {  // vector: Wproj_v, 4 tiles x 3 c = 12 jobs, 3/wave
    bshort8 fv[3][2];
    #pragma unroll
    for (int c=0;c<3;c++)
      #pragma unroll
      for (int kt=0;kt<2;kt++)
        fv[c][kt] = *(const bshort8*)&nv[c][l15*72 + kt*32 + quad*8];
    #pragma unroll
    for (int j=0;j<3;j++) {
      int job = wave*3 + j;
      int c = job>>2, nt = job&3;
      int col = nt*16 + l15;
      floatx4 acc = {0.f,0.f,0.f,0.f};
      #pragma unroll
      for (int kt=0;kt<2;kt++)
        acc = MFMA16(fv[c][kt], *(const bshort8*)&swz[O_WPV + ((nt*2+kt)*64+lane)*8], acc);
      #pragma unroll
      for (int r=0;r<4;r++) out[(n0+quad*4+r)*320 + 128 + col*3 + c] = acc[r];
    }
  }
}

// ---------------------------------------------------------------- launch
extern "C" void kernel_launch(void* const* d_in, const int* in_sizes, int n_in,
                              void* d_out, int out_size, void* d_ws, size_t ws_size,
                              hipStream_t stream) {
  (void)in_sizes; (void)n_in; (void)out_size; (void)ws_size;
  const float* node_input = (const float*)d_in[0];
  const int*   esrc       = (const int*)d_in[1];
  const int*   edst       = (const int*)d_in[2];
  const float* eattr      = (const float*)d_in[3];
  const float* escal      = (const float*)d_in[4];
  const float* Wsrc_s     = (const float*)d_in[5];
  const float* Wsrc_v     = (const float*)d_in[6];
  const float* bsrc       = (const float*)d_in[7];
  const float* Wdst_s     = (const float*)d_in[8];
  const float* Wdst_v     = (const float*)d_in[9];
  const float* rad_W1     = (const float*)d_in[10];
  const float* rad_b1     = (const float*)d_in[11];
  const float* rad_W2     = (const float*)d_in[12];
  const float* rad_off    = (const float*)d_in[13];
  const float* Wact_s     = (const float*)d_in[14];
  const float* bact       = (const float*)d_in[15];
  const float* Wact_v     = (const float*)d_in[16];
  const float* Walpha     = (const float*)d_in[17];
  const float* balpha     = (const float*)d_in[18];
  const float* w_int      = (const float*)d_in[19];
  const float* Wval_s     = (const float*)d_in[20];
  const float* bval       = (const float*)d_in[21];
  const float* Wval_v     = (const float*)d_in[22];
  const float* alpha_dot  = (const float*)d_in[23];
  const float* Wproj_s    = (const float*)d_in[24];
  const float* bproj      = (const float*)d_in[25];
  const float* Wproj_v    = (const float*)d_in[26];
  float* out = (float*)d_out;

  float* ws = (float*)d_ws;
  float* ms_s   = ws;                 // N*128
  float* md_s   = ws + 1280000;       // N*128
  float* ms_v   = ws + 2560000;       // N*192
  float* md_v   = ws + 4480000;       // N*192
  float* den    = ws + 6400000;       // N*8
  float* num    = ws + 6480000;       // N*320 -> ends 9,680,000
  unsigned short* swz = (unsigned short*)(ws + 9680000);   // 210,944 ushorts -> 105,472 floats
  int* cnt  = (int*)(ws + 9785472);   // NN
  int* offs = (int*)(ws + 9795472);   // NN
  int* perm = (int*)(ws + 9805472);   // NE -> ends 9,965,472 floats (~39.9 MB)

  k_prep<<<824, 256, 0, stream>>>(rad_W1, rad_W2, Wact_s, Wact_v, Wval_s, Wval_v, Walpha,
                                  Wsrc_s, Wdst_s, Wsrc_v, Wdst_v, Wproj_s, Wproj_v, swz);
  k_init<<<12500, 256, 0, stream>>>(num, den, cnt);
  k_hist<<<625, 256, 0, stream>>>(edst, cnt);
  k_scan<<<1, 256, 0, stream>>>(cnt, offs);
  k_scatter<<<625, 256, 0, stream>>>(edst, offs, perm);
  node_pre<<<625, 256, 0, stream>>>(node_input, bsrc, swz, ms_s, md_s, ms_v, md_v);
  e_all<<<10000, 256, 0, stream>>>(ms_s, md_s, ms_v, md_v, esrc, edst, perm, eattr, escal,
                                   rad_b1, rad_off, bact, w_int, bval,
                                   balpha, alpha_dot, swz, den, num);
  node_post<<<625, 256, 0, stream>>>(num, den, bproj, swz, out);
}

// Round 10
// 498.779 us; speedup vs baseline: 1.1101x; 1.1101x over previous
//
#include <hip/hip_runtime.h>

#define NN 10000
#define NE 160000
#define INV_SQRT3f 0.57735026918962576f
#define INV_SQRT2f 0.70710678118654752f
#define VPL 640000   // vector plane length (NN*64 floats)

typedef short bshort8 __attribute__((ext_vector_type(8)));
typedef float floatx4 __attribute__((ext_vector_type(4)));
#define MFMA16(a,b,c) __builtin_amdgcn_mfma_f32_16x16x32_bf16((a),(b),(c),0,0,0)

__device__ __forceinline__ float sigm(float x){ return 1.f/(1.f+__expf(-x)); }
__device__ __forceinline__ float siluf(float x){ return x*sigm(x); }
__device__ __forceinline__ float sleaky(float x){ return 0.6f*x + 0.4f*x*(2.f*sigm(x)-1.f); }
__device__ __forceinline__ unsigned short f2bf(float f){
  unsigned u = __float_as_uint(f);
  u += 0x7FFF + ((u>>16)&1);
  return (unsigned short)(u>>16);
}
__device__ __forceinline__ float bf2f(unsigned short h){
  return __uint_as_float(((unsigned)h)<<16);
}

// swizzled-weight segment offsets (in ushorts)
#define O_W1   0
#define O_W2   2048
#define O_WAS  30720
#define O_WAVT 67584
#define O_WAVB 75776
#define O_WVS  83968
#define O_WVVT 108544
#define O_WVVB 116736
#define O_WALP 124928
#define SWZ_TOTAL 149504

// ---------------------------------------------------------------- init
__global__ __launch_bounds__(256) void k_init(float* __restrict__ num,
                                              float* __restrict__ den,
                                              int* __restrict__ cnt) {
  int i = blockIdx.x*256 + threadIdx.x;
  if (i < NN*320) num[i] = 0.f;
  if (i < NN*8) den[i] = 0.f;
  if (i < NN) cnt[i] = 0;
}

// ---------------------------------------------------------------- counting sort of edges by dst
__global__ __launch_bounds__(256) void k_hist(const int* __restrict__ edst,
                                              int* __restrict__ cnt) {
  int e = blockIdx.x*256 + threadIdx.x;
  if (e < NE) atomicAdd(&cnt[edst[e]], 1);
}

__global__ __launch_bounds__(256) void k_scan(const int* __restrict__ cnt,
                                              int* __restrict__ offs) {
  __shared__ int wsum[4];
  const int tid = threadIdx.x;
  const int lane = tid & 63, wave = tid >> 6;
  int v[40]; int s = 0;
  #pragma unroll
  for (int j=0;j<40;j++){ int i = tid*40+j; v[j] = (i<NN)?cnt[i]:0; s += v[j]; }
  int incl = s;
  #pragma unroll
  for (int d=1; d<64; d<<=1) { int t = __shfl_up(incl, d, 64); if (lane>=d) incl += t; }
  if (lane==63) wsum[wave] = incl;
  __syncthreads();
  int wbase = 0;
  for (int w=0; w<wave; ++w) wbase += wsum[w];
  int excl = wbase + incl - s;
  #pragma unroll
  for (int j=0;j<40;j++){ int i = tid*40+j; if (i<NN) offs[i] = excl; excl += v[j]; }
}

__global__ __launch_bounds__(256) void k_scatter(const int* __restrict__ edst,
                                                 int* __restrict__ offs,
                                                 int* __restrict__ perm) {
  int e = blockIdx.x*256 + threadIdx.x;
  if (e < NE) {
    int pos = atomicAdd(&offs[edst[e]], 1);
    perm[pos] = e;
  }
}

// ---------------------------------------------------------------- node pre (fp32 GEMV, R8 form; SoA vector planes)
__global__ __launch_bounds__(256) void node_pre(
    const float* __restrict__ x,
    const float* __restrict__ Wsrc_s, const float* __restrict__ Wsrc_v,
    const float* __restrict__ bsrc,
    const float* __restrict__ Wdst_s, const float* __restrict__ Wdst_v,
    float* __restrict__ ms_s, float* __restrict__ md_s,
    float* __restrict__ ms_v, float* __restrict__ md_v) {
  __shared__ __align__(16) float s_s[128*8];
  __shared__ __align__(16) float s_v[192*8];
  const int tid = threadIdx.x;
  const int n0 = blockIdx.x*8;
  for (int idx = tid; idx < 8*320; idx += 256) {
    int n = idx/320, d = idx - n*320;
    float val = x[(n0+n)*320 + d];
    if (d < 128) s_s[d*8+n] = val;
    else         s_v[(d-128)*8+n] = val;
  }
  __syncthreads();
  {
    int g = tid>>7, j = tid&127;
    float accs[4], accd[4];
    float b = bsrc[j];
    #pragma unroll
    for (int i=0;i<4;i++){ accs[i]=b; accd[i]=0.f; }
    for (int k=0;k<128;k++) {
      float w1 = Wsrc_s[k*128+j], w2 = Wdst_s[k*128+j];
      float4 sv = *(const float4*)&s_s[k*8+g*4];
      accs[0]+=sv.x*w1; accs[1]+=sv.y*w1; accs[2]+=sv.z*w1; accs[3]+=sv.w*w1;
      accd[0]+=sv.x*w2; accd[1]+=sv.y*w2; accd[2]+=sv.z*w2; accd[3]+=sv.w*w2;
    }
    #pragma unroll
    for (int i=0;i<4;i++){ int n=n0+g*4+i; ms_s[n*128+j]=accs[i]; md_s[n*128+j]=accd[i]; }
  }
  if (tid < 192) {
    int c = tid>>6, k = tid&63;
    float accs[8], accd[8];
    #pragma unroll
    for (int e=0;e<8;e++){ accs[e]=0.f; accd[e]=0.f; }
    for (int m=0;m<64;m++) {
      float w1 = Wsrc_v[m*64+k], w2 = Wdst_v[m*64+k];
      float4 v0 = *(const float4*)&s_v[(m*3+c)*8];
      float4 v1 = *(const float4*)&s_v[(m*3+c)*8+4];
      accs[0]+=v0.x*w1; accs[1]+=v0.y*w1; accs[2]+=v0.z*w1; accs[3]+=v0.w*w1;
      accs[4]+=v1.x*w1; accs[5]+=v1.y*w1; accs[6]+=v1.z*w1; accs[7]+=v1.w*w1;
      accd[0]+=v0.x*w2; accd[1]+=v0.y*w2; accd[2]+=v0.z*w2; accd[3]+=v0.w*w2;
      accd[4]+=v1.x*w2; accd[5]+=v1.y*w2; accd[6]+=v1.z*w2; accd[7]+=v1.w*w2;
    }
    // SoA planes: [c][n*64+k] — coalesced over k
    #pragma unroll
    for (int e=0;e<8;e++){
      int n=n0+e;
      ms_v[c*VPL + n*64 + k] = accs[e];
      md_v[c*VPL + n*64 + k] = accd[e];
    }
  }
}

// ---------------------------------------------------------------- weight pre-swizzle (R8 form)
__global__ __launch_bounds__(256) void k_prep(
    const float* __restrict__ W1, const float* __restrict__ W2,
    const float* __restrict__ WAs, const float* __restrict__ WAv,
    const float* __restrict__ WVs, const float* __restrict__ WVv,
    const float* __restrict__ WAl,
    unsigned short* __restrict__ swz) {
  int s = blockIdx.x*256 + threadIdx.x;
  if (s >= SWZ_TOTAL) return;
  const float* src; int base, N, KT, rowOff;
  if      (s < 2048)  { base=O_W1;   src=W1;  N=64;  KT=1; rowOff=0; }
  else if (s < 30720) { base=O_W2;   src=W2;  N=448; KT=2; rowOff=0; }
  else if (s < 67584) { base=O_WAS;  src=WAs; N=192; KT=6; rowOff=0; }
  else if (s < 75776) { base=O_WAVT; src=WAv; N=64;  KT=4; rowOff=0; }
  else if (s < 83968) { base=O_WAVB; src=WAv; N=64;  KT=4; rowOff=128; }
  else if (s < 108544){ base=O_WVS;  src=WVs; N=128; KT=6; rowOff=0; }
  else if (s < 116736){ base=O_WVVT; src=WVv; N=64;  KT=4; rowOff=0; }
  else if (s < 124928){ base=O_WVVB; src=WVv; N=64;  KT=4; rowOff=128; }
  else                { base=O_WALP; src=WAl; N=128; KT=6; rowOff=0; }
  int loc = s - base;
  int j = loc & 7, l = (loc>>3)&63, kt = (loc>>9)%KT, nt = loc/(512*KT);
  int row = kt*32 + (l>>4)*8 + j + rowOff;
  int col = nt*16 + (l&15);
  swz[s] = f2bf(src[row*N + col]);
}

// ---------------------------------------------------------------- fused edge pass (R8 form + SoA vector gather)
__global__ __launch_bounds__(256) void e_all(
    const float* __restrict__ ms_s, const float* __restrict__ md_s,
    const float* __restrict__ ms_v, const float* __restrict__ md_v,
    const int* __restrict__ esrc, const int* __restrict__ edst,
    const int* __restrict__ perm,
    const float* __restrict__ eattr, const float* __restrict__ escal,
    const float* __restrict__ rad_b1, const float* __restrict__ rad_off,
    const float* __restrict__ bact, const float* __restrict__ w_int,
    const float* __restrict__ bval,
    const float* __restrict__ balpha, const float* __restrict__ alpha_dot,
    const unsigned short* __restrict__ swz,
    float* __restrict__ den, float* __restrict__ num) {
  __shared__ __align__(16) char smem[39040];
  unsigned short* sw   = (unsigned short*)smem;           // 16x448
  unsigned short* scb  = (unsigned short*)smem;           // 16x192
  unsigned short* gshb = (unsigned short*)(smem+6144);    // 16x64
  unsigned short* gbb  = (unsigned short*)(smem+8192);    // 3x16x64
  float* vout          = (float*)smem;                    // staging
  unsigned short* ads  = (unsigned short*)(smem+14336);   // 16x200 (ds / vs)
  unsigned short* at1  = (unsigned short*)(smem+20736);   // 16x136 (t1 / t2)
  unsigned short* advb = (unsigned short*)(smem+25088);   // 3x16x136 (dvB / vvB)
  unsigned short* aes  = (unsigned short*)(smem+25088);   // alias (dead pre-B)
  unsigned short* ah   = (unsigned short*)(smem+26368);   // alias (dead pre-B)
  float* s_e0 = (float*)(smem+38144);
  float* s_e1 = (float*)(smem+38208);
  float* s_ex = (float*)(smem+38400);
  int* s_src  = (int*)(smem+38912);
  int* s_dst  = (int*)(smem+38976);
  int* s_eid  = (int*)(smem+38848);
  const int tid  = threadIdx.x;
  const int lane = tid & 63, wave = tid >> 6;
  const int quad = lane >> 4, l15 = lane & 15;
  const int eb = blockIdx.x*16;

  if (tid < 16) {
    int eid = perm[eb+tid];
    s_eid[tid] = eid; s_src[tid] = esrc[eid]; s_dst[tid] = edst[eid];
  }
  __syncthreads();
  if (tid >= 64 && tid < 128) {
    int t = tid-64, e = t>>2, q = t&3;
    float a = eattr[s_eid[e]*4+q];
    if (q == 0) s_e0[e] = a; else s_e1[(q-1)*16+e] = a;
  }
  #pragma unroll
  for (int it = 0; it < 2; ++it) {
    int idx = tid + it*256;
    int e = idx>>5, i = idx&31;
    aes[e*40+i] = f2bf(escal[s_eid[e]*32+i]);
  }
  __syncthreads();

  {
    int nt = wave, col = nt*16 + l15;
    bshort8 a = *(const bshort8*)&aes[l15*40 + quad*8];
    bshort8 b = *(const bshort8*)&swz[O_W1 + (nt*64 + lane)*8];
    float bb = rad_b1[col];
    floatx4 acc = {bb,bb,bb,bb};
    acc = MFMA16(a, b, acc);
    #pragma unroll
    for (int r=0;r<4;r++) ah[(quad*4+r)*72 + col] = f2bf(siluf(acc[r]));
  }
  __syncthreads();

  {
    bshort8 ha0 = *(const bshort8*)&ah[l15*72 + quad*8];
    bshort8 ha1 = *(const bshort8*)&ah[l15*72 + 32 + quad*8];
    #pragma unroll
    for (int t=0;t<7;t++) {
      int nt = wave*7 + t, col = nt*16 + l15;
      float o = rad_off[col];
      floatx4 acc = {o,o,o,o};
      acc = MFMA16(ha0, *(const bshort8*)&swz[O_W2 + ((nt*2+0)*64+lane)*8], acc);
      acc = MFMA16(ha1, *(const bshort8*)&swz[O_W2 + ((nt*2+1)*64+lane)*8], acc);
      #pragma unroll
      for (int r=0;r<4;r++) sw[(quad*4+r)*448 + col] = f2bf(acc[r]);
    }
  }
  __syncthreads();

  #pragma unroll
  for (int it = 0; it < 8; ++it) {
    int t = tid + it*256;
    int m = t&127, e = t>>7;
    float msgs = ms_s[s_src[e]*128+m] + md_s[s_dst[e]*128+m];
    ads[e*200+m] = f2bf(bf2f(sw[e*448+m])*msgs*s_e0[e]);
    at1[e*136+m] = f2bf(bf2f(sw[e*448+128+m])*msgs);
  }
  #pragma unroll
  for (int it = 0; it < 4; ++it) {
    int t = tid + it*256;
    int k = t&63, e = t>>6;
    int sb = s_src[e]*64 + k, db = s_dst[e]*64 + k;   // SoA planes: coalesced over k
    float vx = ms_v[0*VPL+sb] + md_v[0*VPL+db];
    float vy = ms_v[1*VPL+sb] + md_v[1*VPL+db];
    float vz = ms_v[2*VPL+sb] + md_v[2*VPL+db];
    float ex1 = s_e1[0+e], ey1 = s_e1[16+e], ez1 = s_e1[32+e];
    float d = vx*ex1 + vy*ey1 + vz*ez1;
    ads[e*200+128+k] = f2bf(bf2f(sw[e*448+320+k])*d*INV_SQRT3f);
    float w3v = bf2f(sw[e*448+256+k])*s_e0[e];
    float w5  = bf2f(sw[e*448+384+k])*INV_SQRT2f;
    advb[0*2176 + e*136 + k] = f2bf(w3v*vx);
    advb[1*2176 + e*136 + k] = f2bf(w3v*vy);
    advb[2*2176 + e*136 + k] = f2bf(w3v*vz);
    advb[0*2176 + e*136 + 64+k] = f2bf(w5*(vy*ez1 - vz*ey1));
    advb[1*2176 + e*136 + 64+k] = f2bf(w5*(vz*ex1 - vx*ez1));
    advb[2*2176 + e*136 + 64+k] = f2bf(w5*(vx*ey1 - vy*ex1));
  }
  __syncthreads();

  {
    bshort8 fa[6];
    #pragma unroll
    for (int kt=0;kt<6;kt++) fa[kt] = *(const bshort8*)&ads[l15*200 + kt*32 + quad*8];
    #pragma unroll
    for (int t=0;t<2;t++) {
      int h = wave*2 + t;
      int col = h*16 + l15;
      float bb = balpha[col];
      floatx4 acc = {bb,bb,bb,bb};
      #pragma unroll
      for (int kt=0;kt<6;kt++)
        acc = MFMA16(fa[kt], *(const bshort8*)&swz[O_WALP + ((h*6+kt)*64+lane)*8], acc);
      float ad = alpha_dot[col];
      #pragma unroll
      for (int r=0;r<4;r++) {
        float p = sleaky(acc[r])*ad;
        p += __shfl_xor(p, 1);
        p += __shfl_xor(p, 2);
        p += __shfl_xor(p, 4);
        p += __shfl_xor(p, 8);
        if (l15 == 0) {
          int row = quad*4 + r;
          float ex = __expf(p);
          s_ex[row*8+h] = ex;
          atomicAdd(&den[s_dst[row]*8+h], ex);
        }
      }
    }
    #pragma unroll
    for (int t=0;t<3;t++) {
      int nt = wave + 4*t, col = nt*16 + l15;
      float bb = bact[col];
      floatx4 acc = {bb,bb,bb,bb};
      #pragma unroll
      for (int kt=0;kt<6;kt++)
        acc = MFMA16(fa[kt], *(const bshort8*)&swz[O_WAS + ((nt*6+kt)*64+lane)*8], acc);
      #pragma unroll
      for (int r=0;r<4;r++) scb[(quad*4+r)*192 + col] = f2bf(acc[r]);
    }
    bshort8 ft[4];
    #pragma unroll
    for (int kt=0;kt<4;kt++) ft[kt] = *(const bshort8*)&at1[l15*136 + kt*32 + quad*8];
    {
      int nt = wave, col = nt*16 + l15;
      floatx4 acc = {0.f,0.f,0.f,0.f};
      #pragma unroll
      for (int kt=0;kt<4;kt++)
        acc = MFMA16(ft[kt], *(const bshort8*)&swz[O_WAVT + ((nt*4+kt)*64+lane)*8], acc);
      #pragma unroll
      for (int r=0;r<4;r++) gshb[(quad*4+r)*64 + col] = f2bf(acc[r]);
    }
    #pragma unroll
    for (int c=0;c<3;c++) {
      int nt = wave, col = nt*16 + l15;
      floatx4 acc = {0.f,0.f,0.f,0.f};
      #pragma unroll
      for (int kt=0;kt<4;kt++) {
        bshort8 fb = *(const bshort8*)&advb[c*2176 + l15*136 + kt*32 + quad*8];
        acc = MFMA16(fb, *(const bshort8*)&swz[O_WAVB + ((nt*4+kt)*64+lane)*8], acc);
      }
      #pragma unroll
      for (int r=0;r<4;r++) gbb[c*1024 + (quad*4+r)*64 + col] = f2bf(acc[r]);
    }
  }
  __syncthreads();

  #pragma unroll
  for (int it = 0; it < 8; ++it) {
    int t = tid + it*256;
    int m = t&127, e = t>>7;
    float v = siluf(bf2f(scb[e*192+m]));
    ads[e*200+m] = f2bf(w_int[m]*v*s_e0[e]);
    at1[e*136+m] = f2bf(w_int[128+m]*v);
  }
  #pragma unroll
  for (int it = 0; it < 4; ++it) {
    int t = tid + it*256;
    int k = t&63, e = t>>6;
    float sg = sigm(bf2f(scb[e*192+128+k]));
    float gs = bf2f(gshb[e*64+k]);
    float ex1 = s_e1[0+e], ey1 = s_e1[16+e], ez1 = s_e1[32+e];
    float v0 = (gs*ex1 + bf2f(gbb[0*1024 + e*64+k]))*sg;
    float v1 = (gs*ey1 + bf2f(gbb[1*1024 + e*64+k]))*sg;
    float v2 = (gs*ez1 + bf2f(gbb[2*1024 + e*64+k]))*sg;
    float d = v0*ex1 + v1*ey1 + v2*ez1;
    ads[e*200+128+k] = f2bf(w_int[320+k]*d*INV_SQRT3f);
    float w3v = w_int[256+k]*s_e0[e];
    float w5  = w_int[384+k]*INV_SQRT2f;
    advb[0*2176 + e*136 + k] = f2bf(w3v*v0);
    advb[1*2176 + e*136 + k] = f2bf(w3v*v1);
    advb[2*2176 + e*136 + k] = f2bf(w3v*v2);
    advb[0*2176 + e*136 + 64+k] = f2bf(w5*(v1*ez1 - v2*ey1));
    advb[1*2176 + e*136 + 64+k] = f2bf(w5*(v2*ex1 - v0*ez1));
    advb[2*2176 + e*136 + 64+k] = f2bf(w5*(v0*ey1 - v1*ex1));
  }
  __syncthreads();

  {
    bshort8 fa[6];
    #pragma unroll
    for (int kt=0;kt<6;kt++) fa[kt] = *(const bshort8*)&ads[l15*200 + kt*32 + quad*8];
    #pragma unroll
    for (int t=0;t<2;t++) {
      int h = wave + 4*t;
      float bb = bval[h*16 + l15];
      floatx4 acc = {bb,bb,bb,bb};
      #pragma unroll
      for (int kt=0;kt<6;kt++)
        acc = MFMA16(fa[kt], *(const bshort8*)&swz[O_WVS + ((h*6+kt)*64+lane)*8], acc);
      #pragma unroll
      for (int r=0;r<4;r++) {
        int row = quad*4 + r;
        vout[row*128 + h*16 + l15] = acc[r]*s_ex[row*8+h];
      }
    }
  }
  __syncthreads();

  {
    int j = tid & 127, g = tid >> 7;
    int h = j>>4, jj = j&15;
    float acc = 0.f; int cur = s_dst[g*8];
    #pragma unroll
    for (int e = g*8; e < g*8+8; ++e) {
      int d = s_dst[e];
      if (d != cur) { atomicAdd(&num[cur*320 + h*40 + jj], acc); acc = 0.f; cur = d; }
      acc += vout[e*128 + j];
    }
    atomicAdd(&num[cur*320 + h*40 + jj], acc);
  }
  __syncthreads();

  {
    bshort8 ft[4];
    #pragma unroll
    for (int kt=0;kt<4;kt++) ft[kt] = *(const bshort8*)&at1[l15*136 + kt*32 + quad*8];
    floatx4 vsh = {0.f,0.f,0.f,0.f};
    #pragma unroll
    for (int kt=0;kt<4;kt++)
      vsh = MFMA16(ft[kt], *(const bshort8*)&swz[O_WVVT + ((wave*4+kt)*64+lane)*8], vsh);
    int k = wave*16 + l15;
    int h = k>>3, q = k&7;
    #pragma unroll
    for (int c=0;c<3;c++) {
      floatx4 acc = {0.f,0.f,0.f,0.f};
      #pragma unroll
      for (int kt=0;kt<4;kt++) {
        bshort8 fb = *(const bshort8*)&advb[c*2176 + l15*136 + kt*32 + quad*8];
        acc = MFMA16(fb, *(const bshort8*)&swz[O_WVVB + ((wave*4+kt)*64+lane)*8], acc);
      }
      #pragma unroll
      for (int r=0;r<4;r++) {
        int row = quad*4 + r;
        vout[row*192 + h*24 + q*3 + c] =
            (acc[r] + s_e1[c*16+row]*vsh[r]) * s_ex[row*8+h];
      }
    }
  }
  __syncthreads();

  #pragma unroll
  for (int it = 0; it < 2; ++it) {
    int idx = tid + it*256;
    if (idx < 384) {
      int g = idx/192, jj = idx - g*192;
      int h = jj/24, rr = jj - h*24;
      float acc = 0.f; int cur = s_dst[g*8];
      #pragma unroll
      for (int e = g*8; e < g*8+8; ++e) {
        int d = s_dst[e];
        if (d != cur) { atomicAdd(&num[cur*320 + h*40 + 16 + rr], acc); acc = 0.f; cur = d; }
        acc += vout[e*192 + jj];
      }
      atomicAdd(&num[cur*320 + h*40 + 16 + rr], acc);
    }
  }
}

// ---------------------------------------------------------------- node post (fp32 GEMV, R8 form)
__global__ __launch_bounds__(256) void node_post(
    const float* __restrict__ num, const float* __restrict__ den,
    const float* __restrict__ Wproj_s, const float* __restrict__ bproj,
    const float* __restrict__ Wproj_v, float* __restrict__ out) {
  __shared__ __align__(16) float s_ns[128*8];
  __shared__ __align__(16) float s_nv[192*8];
  const int tid = threadIdx.x;
  const int n0 = blockIdx.x*8;
  for (int idx = tid; idx < 8*320; idx += 256) {
    int n = idx/320, j = idx - n*320;
    int h = j/40, r = j - h*40;
    float a = num[(n0+n)*320+j] / (den[(n0+n)*8+h] + 1e-16f);
    if (r < 16) s_ns[(h*16+r)*8+n] = a;
    else        s_nv[(h*24 + (r-16))*8+n] = a;
  }
  __syncthreads();
  {
    int g = tid>>7, j = tid&127;
    float acc[4]; float b = bproj[j];
    #pragma unroll
    for (int i=0;i<4;i++) acc[i]=b;
    for (int k=0;k<128;k++) {
      float wv = Wproj_s[k*128+j];
      float4 s4 = *(const float4*)&s_ns[k*8+g*4];
      acc[0]+=s4.x*wv; acc[1]+=s4.y*wv; acc[2]+=s4.z*wv; acc[3]+=s4.w*wv;
    }
    #pragma unroll
    for (int i=0;i<4;i++) out[(n0+g*4+i)*320 + j] = acc[i];
  }
  if (tid < 192) {
    int c = tid>>6, k = tid&63;
    float acc[8];
    #pragma unroll
    for (int e=0;e<8;e++) acc[e]=0.f;
    for (int m=0;m<64;m++) {
      float wv = Wproj_v[m*64+k];
      float4 v0 = *(const float4*)&s_nv[(m*3+c)*8];
      float4 v1 = *(const float4*)&s_nv[(m*3+c)*8+4];
      acc[0]+=v0.x*wv; acc[1]+=v0.y*wv; acc[2]+=v0.z*wv; acc[3]+=v0.w*wv;
      acc[4]+=v1.x*wv; acc[5]+=v1.y*wv; acc[6]+=v1.z*wv; acc[7]+=v1.w*wv;
    }
    #pragma unroll
    for (int e=0;e<8;e++) out[(n0+e)*320 + 128 + k*3 + c] = acc[e];
  }
}

// ---------------------------------------------------------------- launch
extern "C" void kernel_launch(void* const* d_in, const int* in_sizes, int n_in,
                              void* d_out, int out_size, void* d_ws, size_t ws_size,
                              hipStream_t stream) {
  (void)in_sizes; (void)n_in; (void)out_size; (void)ws_size;
  const float* node_input = (const float*)d_in[0];
  const int*   esrc       = (const int*)d_in[1];
  const int*   edst       = (const int*)d_in[2];
  const float* eattr      = (const float*)d_in[3];
  const float* escal      = (const float*)d_in[4];
  const float* Wsrc_s     = (const float*)d_in[5];
  const float* Wsrc_v     = (const float*)d_in[6];
  const float* bsrc       = (const float*)d_in[7];
  const float* Wdst_s     = (const float*)d_in[8];
  const float* Wdst_v     = (const float*)d_in[9];
  const float* rad_W1     = (const float*)d_in[10];
  const float* rad_b1     = (const float*)d_in[11];
  const float* rad_W2     = (const float*)d_in[12];
  const float* rad_off    = (const float*)d_in[13];
  const float* Wact_s     = (const float*)d_in[14];
  const float* bact       = (const float*)d_in[15];
  const float* Wact_v     = (const float*)d_in[16];
  const float* Walpha     = (const float*)d_in[17];
  const float* balpha     = (const float*)d_in[18];
  const float* w_int      = (const float*)d_in[19];
  const float* Wval_s     = (const float*)d_in[20];
  const float* bval       = (const float*)d_in[21];
  const float* Wval_v     = (const float*)d_in[22];
  const float* alpha_dot  = (const float*)d_in[23];
  const float* Wproj_s    = (const float*)d_in[24];
  const float* bproj      = (const float*)d_in[25];
  const float* Wproj_v    = (const float*)d_in[26];
  float* out = (float*)d_out;

  float* ws = (float*)d_ws;
  float* ms_s   = ws;                 // N*128
  float* md_s   = ws + 1280000;       // N*128
  float* ms_v   = ws + 2560000;       // 3 planes x N*64
  float* md_v   = ws + 4480000;       // 3 planes x N*64
  float* den    = ws + 6400000;       // N*8
  float* num    = ws + 6480000;       // N*320 -> ends 9,680,000
  unsigned short* swz = (unsigned short*)(ws + 9680000);   // 149,504 ushorts
  int* cnt  = (int*)(ws + 9754752);   // NN
  int* offs = (int*)(ws + 9764752);   // NN
  int* perm = (int*)(ws + 9774752);   // NE -> ends 9,934,752 floats (~39.7 MB)

  k_prep<<<584, 256, 0, stream>>>(rad_W1, rad_W2, Wact_s, Wact_v, Wval_s, Wval_v, Walpha, swz);
  k_init<<<12500, 256, 0, stream>>>(num, den, cnt);
  k_hist<<<625, 256, 0, stream>>>(edst, cnt);
  k_scan<<<1, 256, 0, stream>>>(cnt, offs);
  k_scatter<<<625, 256, 0, stream>>>(edst, offs, perm);
  node_pre<<<1250, 256, 0, stream>>>(node_input, Wsrc_s, Wsrc_v, bsrc, Wdst_s, Wdst_v,
                                     ms_s, md_s, ms_v, md_v);
  e_all<<<10000, 256, 0, stream>>>(ms_s, md_s, ms_v, md_v, esrc, edst, perm, eattr, escal,
                                   rad_b1, rad_off, bact, w_int, bval,
                                   balpha, alpha_dot, swz, den, num);
  node_post<<<1250, 256, 0, stream>>>(num, den, Wproj_s, bproj, Wproj_v, out);
}

// Round 11
// 449.940 us; speedup vs baseline: 1.2306x; 1.1085x over previous
//
#include <hip/hip_runtime.h>

#define NN 10000
#define NE 160000
#define INV_SQRT3f 0.57735026918962576f
#define INV_SQRT2f 0.70710678118654752f
#define VPL 640000   // vector plane length (NN*64 floats)

typedef short bshort8 __attribute__((ext_vector_type(8)));
typedef float floatx4 __attribute__((ext_vector_type(4)));
#define MFMA16(a,b,c) __builtin_amdgcn_mfma_f32_16x16x32_bf16((a),(b),(c),0,0,0)

__device__ __forceinline__ float sigm(float x){ return 1.f/(1.f+__expf(-x)); }
__device__ __forceinline__ float siluf(float x){ return x*sigm(x); }
__device__ __forceinline__ float sleaky(float x){ return 0.6f*x + 0.4f*x*(2.f*sigm(x)-1.f); }
// round-half-up bf16 convert: 2 VALU ops vs 5 for RNE, accuracy within half-ulp tie cases
__device__ __forceinline__ unsigned short f2bf(float f){
  return (unsigned short)((__float_as_uint(f) + 0x8000u)>>16);
}
__device__ __forceinline__ float bf2f(unsigned short h){
  return __uint_as_float(((unsigned)h)<<16);
}

// swizzled-weight segment offsets (in ushorts)
#define O_W1   0
#define O_W2   2048
#define O_WAS  30720
#define O_WAVT 67584
#define O_WAVB 75776
#define O_WVS  83968
#define O_WVVT 108544
#define O_WVVB 116736
#define O_WALP 124928
#define SWZ_TOTAL 149504

// ---------------------------------------------------------------- init
__global__ __launch_bounds__(256) void k_init(float* __restrict__ num,
                                              float* __restrict__ den,
                                              int* __restrict__ cnt) {
  int i = blockIdx.x*256 + threadIdx.x;
  if (i < NN*320) num[i] = 0.f;
  if (i < NN*8) den[i] = 0.f;
  if (i < NN) cnt[i] = 0;
}

// ---------------------------------------------------------------- counting sort of edges by dst
__global__ __launch_bounds__(256) void k_hist(const int* __restrict__ edst,
                                              int* __restrict__ cnt) {
  int e = blockIdx.x*256 + threadIdx.x;
  if (e < NE) atomicAdd(&cnt[edst[e]], 1);
}

__global__ __launch_bounds__(256) void k_scan(const int* __restrict__ cnt,
                                              int* __restrict__ offs) {
  __shared__ int wsum[4];
  const int tid = threadIdx.x;
  const int lane = tid & 63, wave = tid >> 6;
  int v[40]; int s = 0;
  #pragma unroll
  for (int j=0;j<40;j++){ int i = tid*40+j; v[j] = (i<NN)?cnt[i]:0; s += v[j]; }
  int incl = s;
  #pragma unroll
  for (int d=1; d<64; d<<=1) { int t = __shfl_up(incl, d, 64); if (lane>=d) incl += t; }
  if (lane==63) wsum[wave] = incl;
  __syncthreads();
  int wbase = 0;
  for (int w=0; w<wave; ++w) wbase += wsum[w];
  int excl = wbase + incl - s;
  #pragma unroll
  for (int j=0;j<40;j++){ int i = tid*40+j; if (i<NN) offs[i] = excl; excl += v[j]; }
}

__global__ __launch_bounds__(256) void k_scatter(const int* __restrict__ edst,
                                                 int* __restrict__ offs,
                                                 int* __restrict__ perm) {
  int e = blockIdx.x*256 + threadIdx.x;
  if (e < NE) {
    int pos = atomicAdd(&offs[edst[e]], 1);
    perm[pos] = e;
  }
}

// ---------------------------------------------------------------- node pre (fp32 GEMV; SoA vector planes)
__global__ __launch_bounds__(256) void node_pre(
    const float* __restrict__ x,
    const float* __restrict__ Wsrc_s, const float* __restrict__ Wsrc_v,
    const float* __restrict__ bsrc,
    const float* __restrict__ Wdst_s, const float* __restrict__ Wdst_v,
    float* __restrict__ ms_s, float* __restrict__ md_s,
    float* __restrict__ ms_v, float* __restrict__ md_v) {
  __shared__ __align__(16) float s_s[128*8];
  __shared__ __align__(16) float s_v[192*8];
  const int tid = threadIdx.x;
  const int n0 = blockIdx.x*8;
  for (int idx = tid; idx < 8*320; idx += 256) {
    int n = idx/320, d = idx - n*320;
    float val = x[(n0+n)*320 + d];
    if (d < 128) s_s[d*8+n] = val;
    else         s_v[(d-128)*8+n] = val;
  }
  __syncthreads();
  {
    int g = tid>>7, j = tid&127;
    float accs[4], accd[4];
    float b = bsrc[j];
    #pragma unroll
    for (int i=0;i<4;i++){ accs[i]=b; accd[i]=0.f; }
    for (int k=0;k<128;k++) {
      float w1 = Wsrc_s[k*128+j], w2 = Wdst_s[k*128+j];
      float4 sv = *(const float4*)&s_s[k*8+g*4];
      accs[0]+=sv.x*w1; accs[1]+=sv.y*w1; accs[2]+=sv.z*w1; accs[3]+=sv.w*w1;
      accd[0]+=sv.x*w2; accd[1]+=sv.y*w2; accd[2]+=sv.z*w2; accd[3]+=sv.w*w2;
    }
    #pragma unroll
    for (int i=0;i<4;i++){ int n=n0+g*4+i; ms_s[n*128+j]=accs[i]; md_s[n*128+j]=accd[i]; }
  }
  if (tid < 192) {
    int c = tid>>6, k = tid&63;
    float accs[8], accd[8];
    #pragma unroll
    for (int e=0;e<8;e++){ accs[e]=0.f; accd[e]=0.f; }
    for (int m=0;m<64;m++) {
      float w1 = Wsrc_v[m*64+k], w2 = Wdst_v[m*64+k];
      float4 v0 = *(const float4*)&s_v[(m*3+c)*8];
      float4 v1 = *(const float4*)&s_v[(m*3+c)*8+4];
      accs[0]+=v0.x*w1; accs[1]+=v0.y*w1; accs[2]+=v0.z*w1; accs[3]+=v0.w*w1;
      accs[4]+=v1.x*w1; accs[5]+=v1.y*w1; accs[6]+=v1.z*w1; accs[7]+=v1.w*w1;
      accd[0]+=v0.x*w2; accd[1]+=v0.y*w2; accd[2]+=v0.z*w2; accd[3]+=v0.w*w2;
      accd[4]+=v1.x*w2; accd[5]+=v1.y*w2; accd[6]+=v1.z*w2; accd[7]+=v1.w*w2;
    }
    #pragma unroll
    for (int e=0;e<8;e++){
      int n=n0+e;
      ms_v[c*VPL + n*64 + k] = accs[e];
      md_v[c*VPL + n*64 + k] = accd[e];
    }
  }
}

// ---------------------------------------------------------------- weight pre-swizzle
__global__ __launch_bounds__(256) void k_prep(
    const float* __restrict__ W1, const float* __restrict__ W2,
    const float* __restrict__ WAs, const float* __restrict__ WAv,
    const float* __restrict__ WVs, const float* __restrict__ WVv,
    const float* __restrict__ WAl,
    unsigned short* __restrict__ swz) {
  int s = blockIdx.x*256 + threadIdx.x;
  if (s >= SWZ_TOTAL) return;
  const float* src; int base, N, KT, rowOff;
  if      (s < 2048)  { base=O_W1;   src=W1;  N=64;  KT=1; rowOff=0; }
  else if (s < 30720) { base=O_W2;   src=W2;  N=448; KT=2; rowOff=0; }
  else if (s < 67584) { base=O_WAS;  src=WAs; N=192; KT=6; rowOff=0; }
  else if (s < 75776) { base=O_WAVT; src=WAv; N=64;  KT=4; rowOff=0; }
  else if (s < 83968) { base=O_WAVB; src=WAv; N=64;  KT=4; rowOff=128; }
  else if (s < 108544){ base=O_WVS;  src=WVs; N=128; KT=6; rowOff=0; }
  else if (s < 116736){ base=O_WVVT; src=WVv; N=64;  KT=4; rowOff=0; }
  else if (s < 124928){ base=O_WVVB; src=WVv; N=64;  KT=4; rowOff=128; }
  else                { base=O_WALP; src=WAl; N=128; KT=6; rowOff=0; }
  int loc = s - base;
  int j = loc & 7, l = (loc>>3)&63, kt = (loc>>9)%KT, nt = loc/(512*KT);
  int row = kt*32 + (l>>4)*8 + j + rowOff;
  int col = nt*16 + (l&15);
  swz[s] = f2bf(src[row*N + col]);
}

// ---------------------------------------------------------------- fused edge pass: CD fused in-register
__global__ __launch_bounds__(256, 4) void e_all(
    const float* __restrict__ ms_s, const float* __restrict__ md_s,
    const float* __restrict__ ms_v, const float* __restrict__ md_v,
    const int* __restrict__ esrc, const int* __restrict__ edst,
    const int* __restrict__ perm,
    const float* __restrict__ eattr, const float* __restrict__ escal,
    const float* __restrict__ rad_b1, const float* __restrict__ rad_off,
    const float* __restrict__ bact, const float* __restrict__ w_int,
    const float* __restrict__ bval,
    const float* __restrict__ balpha, const float* __restrict__ alpha_dot,
    const unsigned short* __restrict__ swz,
    float* __restrict__ den, float* __restrict__ num) {
  __shared__ __align__(16) char smem[39040];
  unsigned short* sw   = (unsigned short*)smem;           // 16x448 (A2->B)
  float* vout          = (float*)smem;                    // staging (E1->F1, E2->F2)
  unsigned short* ads  = (unsigned short*)(smem+14336);   // 16x200 (ds / vs)
  unsigned short* at1  = (unsigned short*)(smem+20736);   // 16x136 (t1 / t2)
  unsigned short* advb = (unsigned short*)(smem+25088);   // 3x16x136 (dvB / vvB)
  unsigned short* aes  = (unsigned short*)(smem+25088);   // alias (dead pre-B)
  unsigned short* ah   = (unsigned short*)(smem+26368);   // alias (dead pre-B)
  float* s_e0 = (float*)(smem+38144);
  float* s_e1 = (float*)(smem+38208);
  float* s_ex = (float*)(smem+38400);
  int* s_src  = (int*)(smem+38912);
  int* s_dst  = (int*)(smem+38976);
  int* s_eid  = (int*)(smem+38848);
  const int tid  = threadIdx.x;
  const int lane = tid & 63, wave = tid >> 6;
  const int quad = lane >> 4, l15 = lane & 15;
  const int eb = blockIdx.x*16;

  if (tid < 16) {
    int eid = perm[eb+tid];
    s_eid[tid] = eid; s_src[tid] = esrc[eid]; s_dst[tid] = edst[eid];
  }
  __syncthreads();
  if (tid >= 64 && tid < 128) {
    int t = tid-64, e = t>>2, q = t&3;
    float a = eattr[s_eid[e]*4+q];
    if (q == 0) s_e0[e] = a; else s_e1[(q-1)*16+e] = a;
  }
  #pragma unroll
  for (int it = 0; it < 2; ++it) {
    int idx = tid + it*256;
    int e = idx>>5, i = idx&31;
    aes[e*40+i] = f2bf(escal[s_eid[e]*32+i]);
  }
  __syncthreads();

  // ---- A1: h = silu(escal@W1+b1)
  {
    int nt = wave, col = nt*16 + l15;
    bshort8 a = *(const bshort8*)&aes[l15*40 + quad*8];
    bshort8 b = *(const bshort8*)&swz[O_W1 + (nt*64 + lane)*8];
    float bb = rad_b1[col];
    floatx4 acc = {bb,bb,bb,bb};
    acc = MFMA16(a, b, acc);
    #pragma unroll
    for (int r=0;r<4;r++) ah[(quad*4+r)*72 + col] = f2bf(siluf(acc[r]));
  }
  __syncthreads();

  // ---- A2: full w (448 cols)
  {
    bshort8 ha0 = *(const bshort8*)&ah[l15*72 + quad*8];
    bshort8 ha1 = *(const bshort8*)&ah[l15*72 + 32 + quad*8];
    #pragma unroll
    for (int t=0;t<7;t++) {
      int nt = wave*7 + t, col = nt*16 + l15;
      float o = rad_off[col];
      floatx4 acc = {o,o,o,o};
      acc = MFMA16(ha0, *(const bshort8*)&swz[O_W2 + ((nt*2+0)*64+lane)*8], acc);
      acc = MFMA16(ha1, *(const bshort8*)&swz[O_W2 + ((nt*2+1)*64+lane)*8], acc);
      #pragma unroll
      for (int r=0;r<4;r++) sw[(quad*4+r)*448 + col] = f2bf(acc[r]);
    }
  }
  __syncthreads();

  // ---- B: dtp1 elementwise + gather -> ads/at1/advb
  #pragma unroll
  for (int it = 0; it < 8; ++it) {
    int t = tid + it*256;
    int m = t&127, e = t>>7;
    float msgs = ms_s[s_src[e]*128+m] + md_s[s_dst[e]*128+m];
    ads[e*200+m] = f2bf(bf2f(sw[e*448+m])*msgs*s_e0[e]);
    at1[e*136+m] = f2bf(bf2f(sw[e*448+128+m])*msgs);
  }
  #pragma unroll
  for (int it = 0; it < 4; ++it) {
    int t = tid + it*256;
    int k = t&63, e = t>>6;
    int sb = s_src[e]*64 + k, db = s_dst[e]*64 + k;
    float vx = ms_v[0*VPL+sb] + md_v[0*VPL+db];
    float vy = ms_v[1*VPL+sb] + md_v[1*VPL+db];
    float vz = ms_v[2*VPL+sb] + md_v[2*VPL+db];
    float ex1 = s_e1[0+e], ey1 = s_e1[16+e], ez1 = s_e1[32+e];
    float d = vx*ex1 + vy*ey1 + vz*ez1;
    ads[e*200+128+k] = f2bf(bf2f(sw[e*448+320+k])*d*INV_SQRT3f);
    float w3v = bf2f(sw[e*448+256+k])*s_e0[e];
    float w5  = bf2f(sw[e*448+384+k])*INV_SQRT2f;
    advb[0*2176 + e*136 + k] = f2bf(w3v*vx);
    advb[1*2176 + e*136 + k] = f2bf(w3v*vy);
    advb[2*2176 + e*136 + k] = f2bf(w3v*vz);
    advb[0*2176 + e*136 + 64+k] = f2bf(w5*(vy*ez1 - vz*ey1));
    advb[1*2176 + e*136 + 64+k] = f2bf(w5*(vz*ex1 - vx*ez1));
    advb[2*2176 + e*136 + 64+k] = f2bf(w5*(vx*ey1 - vy*ex1));
  }
  __syncthreads();

  // ---- CD (fused): all MFMAs with fragments in regs, then activations + dtp2 writes
  floatx4 sc0, sc1, sc2, gsa, gb0, gb1, gb2;
  {
    bshort8 fa[6];
    #pragma unroll
    for (int kt=0;kt<6;kt++) fa[kt] = *(const bshort8*)&ads[l15*200 + kt*32 + quad*8];
    // alpha logits + ex/den (completes before the overwrite barrier)
    #pragma unroll
    for (int t=0;t<2;t++) {
      int h = wave*2 + t;
      int col = h*16 + l15;
      float bb = balpha[col];
      floatx4 acc = {bb,bb,bb,bb};
      #pragma unroll
      for (int kt=0;kt<6;kt++)
        acc = MFMA16(fa[kt], *(const bshort8*)&swz[O_WALP + ((h*6+kt)*64+lane)*8], acc);
      float ad = alpha_dot[col];
      #pragma unroll
      for (int r=0;r<4;r++) {
        float p = sleaky(acc[r])*ad;
        p += __shfl_xor(p, 1);
        p += __shfl_xor(p, 2);
        p += __shfl_xor(p, 4);
        p += __shfl_xor(p, 8);
        if (l15 == 0) {
          int row = quad*4 + r;
          float ex = __expf(p);
          s_ex[row*8+h] = ex;
          atomicAdd(&den[s_dst[row]*8+h], ex);
        }
      }
    }
    // scal tiles: nt = wave (cols 0-63), wave+4 (64-127), wave+8 (128-191)
    {
      float bb = bact[wave*16 + l15];
      floatx4 a0 = {bb,bb,bb,bb};
      #pragma unroll
      for (int kt=0;kt<6;kt++)
        a0 = MFMA16(fa[kt], *(const bshort8*)&swz[O_WAS + ((wave*6+kt)*64+lane)*8], a0);
      sc0 = a0;
    }
    {
      float bb = bact[(wave+4)*16 + l15];
      floatx4 a1 = {bb,bb,bb,bb};
      #pragma unroll
      for (int kt=0;kt<6;kt++)
        a1 = MFMA16(fa[kt], *(const bshort8*)&swz[O_WAS + (((wave+4)*6+kt)*64+lane)*8], a1);
      sc1 = a1;
    }
    {
      float bb = bact[(wave+8)*16 + l15];
      floatx4 a2 = {bb,bb,bb,bb};
      #pragma unroll
      for (int kt=0;kt<6;kt++)
        a2 = MFMA16(fa[kt], *(const bshort8*)&swz[O_WAS + (((wave+8)*6+kt)*64+lane)*8], a2);
      sc2 = a2;
    }
    bshort8 ft[4];
    #pragma unroll
    for (int kt=0;kt<4;kt++) ft[kt] = *(const bshort8*)&at1[l15*136 + kt*32 + quad*8];
    {
      floatx4 acc = {0.f,0.f,0.f,0.f};
      #pragma unroll
      for (int kt=0;kt<4;kt++)
        acc = MFMA16(ft[kt], *(const bshort8*)&swz[O_WAVT + ((wave*4+kt)*64+lane)*8], acc);
      gsa = acc;
    }
    #pragma unroll
    for (int c=0;c<3;c++) {
      floatx4 acc = {0.f,0.f,0.f,0.f};
      #pragma unroll
      for (int kt=0;kt<4;kt++) {
        bshort8 fb = *(const bshort8*)&advb[c*2176 + l15*136 + kt*32 + quad*8];
        acc = MFMA16(fb, *(const bshort8*)&swz[O_WAVB + ((wave*4+kt)*64+lane)*8], acc);
      }
      if (c==0) gb0 = acc; else if (c==1) gb1 = acc; else gb2 = acc;
    }
  }
  __syncthreads();   // all fragment reads done; now safe to overwrite ads/at1/advb

  {
    const int k = wave*16 + l15;       // 0..63
    #pragma unroll
    for (int r=0;r<4;r++) {
      int row = quad*4 + r;
      float e0 = s_e0[row];
      { // silu path, tile t0: m = k
        float v = siluf(sc0[r]);
        ads[row*200+k] = f2bf(w_int[k]*v*e0);
        at1[row*136+k] = f2bf(w_int[128+k]*v);
      }
      { // silu path, tile t1: m = 64+k
        int m = 64+k;
        float v = siluf(sc1[r]);
        ads[row*200+m] = f2bf(w_int[m]*v*e0);
        at1[row*136+m] = f2bf(w_int[128+m]*v);
      }
      { // gated vector path (tile t2 gives scal[128+k])
        float sg = sigm(sc2[r]);
        float gs = gsa[r];
        float ex1 = s_e1[0+row], ey1 = s_e1[16+row], ez1 = s_e1[32+row];
        float v0 = (gs*ex1 + gb0[r])*sg;
        float v1 = (gs*ey1 + gb1[r])*sg;
        float v2 = (gs*ez1 + gb2[r])*sg;
        float d = v0*ex1 + v1*ey1 + v2*ez1;
        ads[row*200+128+k] = f2bf(w_int[320+k]*d*INV_SQRT3f);
        float w3v = w_int[256+k]*e0;
        float w5  = w_int[384+k]*INV_SQRT2f;
        advb[0*2176 + row*136 + k] = f2bf(w3v*v0);
        advb[1*2176 + row*136 + k] = f2bf(w3v*v1);
        advb[2*2176 + row*136 + k] = f2bf(w3v*v2);
        advb[0*2176 + row*136 + 64+k] = f2bf(w5*(v1*ez1 - v2*ey1));
        advb[1*2176 + row*136 + 64+k] = f2bf(w5*(v2*ex1 - v0*ez1));
        advb[2*2176 + row*136 + 64+k] = f2bf(w5*(v0*ey1 - v1*ex1));
      }
    }
  }
  __syncthreads();

  // ---- E1: scalar-out MFMAs -> vout staging (x ex)
  {
    bshort8 fa[6];
    #pragma unroll
    for (int kt=0;kt<6;kt++) fa[kt] = *(const bshort8*)&ads[l15*200 + kt*32 + quad*8];
    #pragma unroll
    for (int t=0;t<2;t++) {
      int h = wave + 4*t;
      float bb = bval[h*16 + l15];
      floatx4 acc = {bb,bb,bb,bb};
      #pragma unroll
      for (int kt=0;kt<6;kt++)
        acc = MFMA16(fa[kt], *(const bshort8*)&swz[O_WVS + ((h*6+kt)*64+lane)*8], acc);
      #pragma unroll
      for (int r=0;r<4;r++) {
        int row = quad*4 + r;
        vout[row*128 + h*16 + l15] = acc[r]*s_ex[row*8+h];
      }
    }
  }
  __syncthreads();

  // ---- F1: run-compressed scalar scatter
  {
    int j = tid & 127, g = tid >> 7;
    int h = j>>4, jj = j&15;
    float acc = 0.f; int cur = s_dst[g*8];
    #pragma unroll
    for (int e = g*8; e < g*8+8; ++e) {
      int d = s_dst[e];
      if (d != cur) { atomicAdd(&num[cur*320 + h*40 + jj], acc); acc = 0.f; cur = d; }
      acc += vout[e*128 + j];
    }
    atomicAdd(&num[cur*320 + h*40 + jj], acc);
  }
  __syncthreads();

  // ---- E2: vector MFMAs -> vout staging (x ex)
  {
    bshort8 ft[4];
    #pragma unroll
    for (int kt=0;kt<4;kt++) ft[kt] = *(const bshort8*)&at1[l15*136 + kt*32 + quad*8];
    floatx4 vsh = {0.f,0.f,0.f,0.f};
    #pragma unroll
    for (int kt=0;kt<4;kt++)
      vsh = MFMA16(ft[kt], *(const bshort8*)&swz[O_WVVT + ((wave*4+kt)*64+lane)*8], vsh);
    int k = wave*16 + l15;
    int h = k>>3, q = k&7;
    #pragma unroll
    for (int c=0;c<3;c++) {
      floatx4 acc = {0.f,0.f,0.f,0.f};
      #pragma unroll
      for (int kt=0;kt<4;kt++) {
        bshort8 fb = *(const bshort8*)&advb[c*2176 + l15*136 + kt*32 + quad*8];
        acc = MFMA16(fb, *(const bshort8*)&swz[O_WVVB + ((wave*4+kt)*64+lane)*8], acc);
      }
      #pragma unroll
      for (int r=0;r<4;r++) {
        int row = quad*4 + r;
        vout[row*192 + h*24 + q*3 + c] =
            (acc[r] + s_e1[c*16+row]*vsh[r]) * s_ex[row*8+h];
      }
    }
  }
  __syncthreads();

  // ---- F2: run-compressed vector scatter
  #pragma unroll
  for (int it = 0; it < 2; ++it) {
    int idx = tid + it*256;
    if (idx < 384) {
      int g = idx/192, jj = idx - g*192;
      int h = jj/24, rr = jj - h*24;
      float acc = 0.f; int cur = s_dst[g*8];
      #pragma unroll
      for (int e = g*8; e < g*8+8; ++e) {
        int d = s_dst[e];
        if (d != cur) { atomicAdd(&num[cur*320 + h*40 + 16 + rr], acc); acc = 0.f; cur = d; }
        acc += vout[e*192 + jj];
      }
      atomicAdd(&num[cur*320 + h*40 + 16 + rr], acc);
    }
  }
}

// ---------------------------------------------------------------- node post (fp32 GEMV)
__global__ __launch_bounds__(256) void node_post(
    const float* __restrict__ num, const float* __restrict__ den,
    const float* __restrict__ Wproj_s, const float* __restrict__ bproj,
    const float* __restrict__ Wproj_v, float* __restrict__ out) {
  __shared__ __align__(16) float s_ns[128*8];
  __shared__ __align__(16) float s_nv[192*8];
  const int tid = threadIdx.x;
  const int n0 = blockIdx.x*8;
  for (int idx = tid; idx < 8*320; idx += 256) {
    int n = idx/320, j = idx - n*320;
    int h = j/40, r = j - h*40;
    float a = num[(n0+n)*320+j] / (den[(n0+n)*8+h] + 1e-16f);
    if (r < 16) s_ns[(h*16+r)*8+n] = a;
    else        s_nv[(h*24 + (r-16))*8+n] = a;
  }
  __syncthreads();
  {
    int g = tid>>7, j = tid&127;
    float acc[4]; float b = bproj[j];
    #pragma unroll
    for (int i=0;i<4;i++) acc[i]=b;
    for (int k=0;k<128;k++) {
      float wv = Wproj_s[k*128+j];
      float4 s4 = *(const float4*)&s_ns[k*8+g*4];
      acc[0]+=s4.x*wv; acc[1]+=s4.y*wv; acc[2]+=s4.z*wv; acc[3]+=s4.w*wv;
    }
    #pragma unroll
    for (int i=0;i<4;i++) out[(n0+g*4+i)*320 + j] = acc[i];
  }
  if (tid < 192) {
    int c = tid>>6, k = tid&63;
    float acc[8];
    #pragma unroll
    for (int e=0;e<8;e++) acc[e]=0.f;
    for (int m=0;m<64;m++) {
      float wv = Wproj_v[m*64+k];
      float4 v0 = *(const float4*)&s_nv[(m*3+c)*8];
      float4 v1 = *(const float4*)&s_nv[(m*3+c)*8+4];
      acc[0]+=v0.x*wv; acc[1]+=v0.y*wv; acc[2]+=v0.z*wv; acc[3]+=v0.w*wv;
      acc[4]+=v1.x*wv; acc[5]+=v1.y*wv; acc[6]+=v1.z*wv; acc[7]+=v1.w*wv;
    }
    #pragma unroll
    for (int e=0;e<8;e++) out[(n0+e)*320 + 128 + k*3 + c] = acc[e];
  }
}

// ---------------------------------------------------------------- launch
extern "C" void kernel_launch(void* const* d_in, const int* in_sizes, int n_in,
                              void* d_out, int out_size, void* d_ws, size_t ws_size,
                              hipStream_t stream) {
  (void)in_sizes; (void)n_in; (void)out_size; (void)ws_size;
  const float* node_input = (const float*)d_in[0];
  const int*   esrc       = (const int*)d_in[1];
  const int*   edst       = (const int*)d_in[2];
  const float* eattr      = (const float*)d_in[3];
  const float* escal      = (const float*)d_in[4];
  const float* Wsrc_s     = (const float*)d_in[5];
  const float* Wsrc_v     = (const float*)d_in[6];
  const float* bsrc       = (const float*)d_in[7];
  const float* Wdst_s     = (const float*)d_in[8];
  const float* Wdst_v     = (const float*)d_in[9];
  const float* rad_W1     = (const float*)d_in[10];
  const float* rad_b1     = (const float*)d_in[11];
  const float* rad_W2     = (const float*)d_in[12];
  const float* rad_off    = (const float*)d_in[13];
  const float* Wact_s     = (const float*)d_in[14];
  const float* bact       = (const float*)d_in[15];
  const float* Wact_v     = (const float*)d_in[16];
  const float* Walpha     = (const float*)d_in[17];
  const float* balpha     = (const float*)d_in[18];
  const float* w_int      = (const float*)d_in[19];
  const float* Wval_s     = (const float*)d_in[20];
  const float* bval       = (const float*)d_in[21];
  const float* Wval_v     = (const float*)d_in[22];
  const float* alpha_dot  = (const float*)d_in[23];
  const float* Wproj_s    = (const float*)d_in[24];
  const float* bproj      = (const float*)d_in[25];
  const float* Wproj_v    = (const float*)d_in[26];
  float* out = (float*)d_out;

  float* ws = (float*)d_ws;
  float* ms_s   = ws;                 // N*128
  float* md_s   = ws + 1280000;       // N*128
  float* ms_v   = ws + 2560000;       // 3 planes x N*64
  float* md_v   = ws + 4480000;       // 3 planes x N*64
  float* den    = ws + 6400000;       // N*8
  float* num    = ws + 6480000;       // N*320 -> ends 9,680,000
  unsigned short* swz = (unsigned short*)(ws + 9680000);   // 149,504 ushorts
  int* cnt  = (int*)(ws + 9754752);   // NN
  int* offs = (int*)(ws + 9764752);   // NN
  int* perm = (int*)(ws + 9774752);   // NE -> ends 9,934,752 floats (~39.7 MB)

  k_prep<<<584, 256, 0, stream>>>(rad_W1, rad_W2, Wact_s, Wact_v, Wval_s, Wval_v, Walpha, swz);
  k_init<<<12500, 256, 0, stream>>>(num, den, cnt);
  k_hist<<<625, 256, 0, stream>>>(edst, cnt);
  k_scan<<<1, 256, 0, stream>>>(cnt, offs);
  k_scatter<<<625, 256, 0, stream>>>(edst, offs, perm);
  node_pre<<<1250, 256, 0, stream>>>(node_input, Wsrc_s, Wsrc_v, bsrc, Wdst_s, Wdst_v,
                                     ms_s, md_s, ms_v, md_v);
  e_all<<<10000, 256, 0, stream>>>(ms_s, md_s, ms_v, md_v, esrc, edst, perm, eattr, escal,
                                   rad_b1, rad_off, bact, w_int, bval,
                                   balpha, alpha_dot, swz, den, num);
  node_post<<<1250, 256, 0, stream>>>(num, den, Wproj_s, bproj, Wproj_v, out);
}